// Round 1
// baseline (157.155 us; speedup 1.0000x reference)
//
#include <hip/hip_runtime.h>

// Chamfer distance, B=8, N=M=8192, 3-D fp32 points.
// d2(x,y) = xx + (yy - 2 x.y). Targets pre-scaled to (-2y, yy) so the
// inner loop is 3 FMA + 1 min per pair. sqrt hoisted out of the pair loop
// (monotonic). Per-direction mins combined across y-splits via atomicMin
// on an order-preserving uint mapping of float.

#define BB 8
#define NN 8192
#define NPTS (BB*NN)      // 65536
#define YSPLIT 4
#define YC (NN/YSPLIT)    // 2048
#define XCHUNK 8          // 8192 / (BLK*RX)
#define RX 4
#define BLK 256

__device__ __forceinline__ unsigned f2mono(float f) {
    unsigned u = __float_as_uint(f);
    return (u & 0x80000000u) ? ~u : (u | 0x80000000u);
}
__device__ __forceinline__ float mono2f(unsigned u) {
    unsigned b = (u & 0x80000000u) ? (u ^ 0x80000000u) : ~u;
    return __uint_as_float(b);
}

__global__ void pack_kernel(const float* __restrict__ x, const float* __restrict__ y,
                            float4* __restrict__ rawx, float4* __restrict__ rawy,
                            float4* __restrict__ sclx, float4* __restrict__ scly) {
    int i = blockIdx.x * blockDim.x + threadIdx.x;   // 0 .. 2*NPTS-1
    const float* src;
    float4 *raw, *scl;
    int j;
    if (i < NPTS) { src = x; raw = rawx; scl = sclx; j = i; }
    else          { src = y; raw = rawy; scl = scly; j = i - NPTS; }
    float f0 = src[3*j], f1 = src[3*j+1], f2 = src[3*j+2];
    float ss = f0*f0 + f1*f1 + f2*f2;
    raw[j] = make_float4(f0, f1, f2, ss);
    scl[j] = make_float4(-2.f*f0, -2.f*f1, -2.f*f2, ss);
}

// grid: (XCHUNK*YSPLIT, BB, 2); block: BLK
__global__ __launch_bounds__(BLK) void
main_kernel(const float4* __restrict__ rawx, const float4* __restrict__ rawy,
            const float4* __restrict__ sclx, const float4* __restrict__ scly,
            unsigned* __restrict__ mind) {
    __shared__ float4 sh[YC];            // 32 KB
    const int dir = blockIdx.z;          // 0: queries=x targets=y, 1: swapped
    const int b   = blockIdx.y;
    const int xc  = blockIdx.x / YSPLIT;
    const int yc  = blockIdx.x % YSPLIT;
    const float4* Q = dir ? rawy : rawx;
    const float4* T = dir ? sclx : scly;
    unsigned* md = mind + dir * NPTS;
    const int t = threadIdx.x;

    // stage target chunk into LDS (coalesced float4 loads)
    const int tb = b * NN + yc * YC;
#pragma unroll
    for (int s = 0; s < YC / BLK; ++s)
        sh[t + s * BLK] = T[tb + t + s * BLK];
    __syncthreads();

    // load RX query points into registers
    float qx[RX], qy[RX], qz[RX], m[RX];
    const int qb = b * NN + xc * (BLK * RX) + t;
#pragma unroll
    for (int k = 0; k < RX; ++k) {
        float4 q = Q[qb + k * BLK];
        qx[k] = q.x; qy[k] = q.y; qz[k] = q.z;
        m[k] = 3.4e38f;
    }

#pragma unroll 4
    for (int j = 0; j < YC; ++j) {
        float4 yv = sh[j];               // wave-uniform broadcast read
#pragma unroll
        for (int k = 0; k < RX; ++k) {
            float tv = fmaf(qx[k], yv.x, yv.w);
            tv = fmaf(qy[k], yv.y, tv);
            tv = fmaf(qz[k], yv.z, tv);
            m[k] = fminf(m[k], tv);
        }
    }

#pragma unroll
    for (int k = 0; k < RX; ++k)
        atomicMin(&md[qb + k * BLK], f2mono(m[k]));
}

// grid: 16 blocks (dir*8+b); block: BLK. bsums[idx] = sum of dists.
__global__ void fin_a(const float4* __restrict__ rawx, const float4* __restrict__ rawy,
                      const unsigned* __restrict__ mind, float* __restrict__ bsums) {
    __shared__ float red[BLK / 64];
    const int idx = blockIdx.x;
    const int dir = idx >> 3, b = idx & 7;
    const float4* Q = dir ? rawy : rawx;
    const unsigned* md = mind + dir * NPTS;
    const int t = threadIdx.x;
    float s = 0.f;
    for (int k = 0; k < NN / BLK; ++k) {
        int i = b * NN + t + k * BLK;
        float v  = mono2f(md[i]);
        float d2 = Q[i].w + v;           // xx + (yy - 2 x.y)
        s += sqrtf(d2 + 1e-10f);
    }
    for (int off = 32; off; off >>= 1) s += __shfl_down(s, off, 64);
    if ((t & 63) == 0) red[t >> 6] = s;
    __syncthreads();
    if (t == 0) {
        float tot = 0.f;
        for (int w = 0; w < BLK / 64; ++w) tot += red[w];
        bsums[idx] = tot;
    }
}

__global__ void fin_b(const float* __restrict__ bsums, float* __restrict__ out) {
    if (threadIdx.x == 0 && blockIdx.x == 0) {
        float s = 0.f;
        for (int b = 0; b < BB; ++b) s += fmaxf(bsums[b], bsums[BB + b]);
        out[0] = s * (1.0f / (float)NN);
    }
}

extern "C" void kernel_launch(void* const* d_in, const int* in_sizes, int n_in,
                              void* d_out, int out_size, void* d_ws, size_t ws_size,
                              hipStream_t stream) {
    const float* x = (const float*)d_in[0];
    const float* y = (const float*)d_in[1];
    float* out = (float*)d_out;

    char* ws = (char*)d_ws;
    float4* rawx = (float4*)ws;
    float4* rawy = rawx + NPTS;
    float4* sclx = rawy + NPTS;
    float4* scly = sclx + NPTS;
    unsigned* mind = (unsigned*)(scly + NPTS);   // 2*NPTS uints
    float* bsums = (float*)(mind + 2 * NPTS);    // 16 floats

    hipMemsetAsync(mind, 0xFF, 2 * NPTS * sizeof(unsigned), stream);
    pack_kernel<<<(2 * NPTS) / BLK, BLK, 0, stream>>>(x, y, rawx, rawy, sclx, scly);
    main_kernel<<<dim3(XCHUNK * YSPLIT, BB, 2), BLK, 0, stream>>>(rawx, rawy, sclx, scly, mind);
    fin_a<<<16, BLK, 0, stream>>>(rawx, rawy, mind, bsums);
    fin_b<<<1, 64, 0, stream>>>(bsums, out);
}

// Round 2
// 148.951 us; speedup vs baseline: 1.0551x; 1.0551x over previous
//
#include <hip/hip_runtime.h>

// Chamfer distance, B=8, N=M=8192, 3-D fp32 points.
// d2(x,y) = xx + (yy - 2 x.y). Targets pre-scaled to (-2y, yy): inner loop is
// 3 FMA per pair, two pairs share one v_min3. sqrt hoisted out (monotone).
// Per-direction mins combined across y-splits via atomicMin on an
// order-preserving uint mapping of float.

#define BB 8
#define NN 8192
#define NPTS (BB*NN)      // 65536
#define YSPLIT 8
#define YC (NN/YSPLIT)    // 1024
#define RX 8
#define BLK 256
#define XCHUNK (NN/(BLK*RX))   // 4

__device__ __forceinline__ unsigned f2mono(float f) {
    unsigned u = __float_as_uint(f);
    return (u & 0x80000000u) ? ~u : (u | 0x80000000u);
}
__device__ __forceinline__ float mono2f(unsigned u) {
    unsigned b = (u & 0x80000000u) ? (u ^ 0x80000000u) : ~u;
    return __uint_as_float(b);
}

// grid 512, block 256. Also initializes mind (0xFF = +inf in mono space) and bsums.
__global__ void pack_kernel(const float* __restrict__ x, const float* __restrict__ y,
                            float4* __restrict__ rawx, float4* __restrict__ rawy,
                            float4* __restrict__ sclx, float4* __restrict__ scly,
                            float* __restrict__ ss, unsigned* __restrict__ mind,
                            float* __restrict__ bsums) {
    int i = blockIdx.x * blockDim.x + threadIdx.x;   // 0 .. 2*NPTS-1
    if (i < 16) bsums[i] = 0.f;
    mind[i] = 0xFFFFFFFFu;
    const float* src;
    float4 *raw, *scl;
    int j;
    if (i < NPTS) { src = x; raw = rawx; scl = sclx; j = i; }
    else          { src = y; raw = rawy; scl = scly; j = i - NPTS; }
    float f0 = src[3*j], f1 = src[3*j+1], f2 = src[3*j+2];
    float sq = f0*f0 + f1*f1 + f2*f2;
    raw[j] = make_float4(f0, f1, f2, sq);
    scl[j] = make_float4(-2.f*f0, -2.f*f1, -2.f*f2, sq);
    ss[i] = sq;
}

// grid: (XCHUNK*YSPLIT=32, BB, 2); block: BLK
__global__ __launch_bounds__(BLK) void
main_kernel(const float4* __restrict__ rawx, const float4* __restrict__ rawy,
            const float4* __restrict__ sclx, const float4* __restrict__ scly,
            unsigned* __restrict__ mind) {
    __shared__ float4 sh[YC + 2];        // 16 KB + pad (prefetch overrun)
    const int dir = blockIdx.z;          // 0: queries=x targets=y, 1: swapped
    const int b   = blockIdx.y;
    const int xc  = blockIdx.x >> 3;     // [0, XCHUNK)
    const int yc  = blockIdx.x & 7;      // [0, YSPLIT)
    const float4* Q = dir ? rawy : rawx;
    const float4* T = dir ? sclx : scly;
    unsigned* md = mind + dir * NPTS;
    const int t = threadIdx.x;

    // stage target chunk into LDS (coalesced float4 loads)
    const int tb = b * NN + yc * YC;
#pragma unroll
    for (int s = 0; s < YC / BLK; ++s)
        sh[t + s * BLK] = T[tb + t + s * BLK];
    if (t < 2) sh[YC + t] = make_float4(0.f, 0.f, 0.f, 0.f);
    __syncthreads();

    // RX query points in registers
    float qx[RX], qy[RX], qz[RX], m[RX];
    const int qb = b * NN + xc * (BLK * RX) + t;
#pragma unroll
    for (int k = 0; k < RX; ++k) {
        float4 q = Q[qb + k * BLK];
        qx[k] = q.x; qy[k] = q.y; qz[k] = q.z;
        m[k] = 3.4e38f;
    }

    // software-pipelined: prefetch next 2 targets while computing current 2
    float4 a = sh[0], bb = sh[1];
#pragma unroll 4
    for (int j = 0; j < YC; j += 2) {
        float4 a2 = sh[j + 2], b2 = sh[j + 3];   // prefetch (pad at end)
#pragma unroll
        for (int k = 0; k < RX; ++k) {
            float t0 = fmaf(qx[k], a.x, a.w);
            t0 = fmaf(qy[k], a.y, t0);
            t0 = fmaf(qz[k], a.z, t0);
            float t1 = fmaf(qx[k], bb.x, bb.w);
            t1 = fmaf(qy[k], bb.y, t1);
            t1 = fmaf(qz[k], bb.z, t1);
            m[k] = fminf(fminf(t0, t1), m[k]);   // v_min3_f32
        }
        a = a2; bb = b2;
    }

#pragma unroll
    for (int k = 0; k < RX; ++k)
        atomicMin(&md[qb + k * BLK], f2mono(m[k]));
}

// grid: 256 blocks = 16 (dir,b) groups x 16 slices; block BLK.
// Partial sums of sqrt(ss + min + eps) accumulated into bsums[16] via atomicAdd.
#define SLICES 16
__global__ void fin_a(const float* __restrict__ ss,
                      const unsigned* __restrict__ mind, float* __restrict__ bsums) {
    __shared__ float red[BLK / 64];
    const int grp = blockIdx.x >> 4;       // dir*8+b
    const int sl  = blockIdx.x & 15;
    const int t = threadIdx.x;
    const int base = grp * NN + sl * (NN / SLICES);   // ss and mind share layout
    float s = 0.f;
#pragma unroll
    for (int k = 0; k < NN / SLICES / BLK; ++k) {     // 2 iters
        int i = base + t + k * BLK;
        float v = mono2f(mind[i]);
        s += sqrtf(ss[i] + v + 1e-10f);
    }
    for (int off = 32; off; off >>= 1) s += __shfl_down(s, off, 64);
    if ((t & 63) == 0) red[t >> 6] = s;
    __syncthreads();
    if (t == 0) {
        float tot = 0.f;
        for (int w = 0; w < BLK / 64; ++w) tot += red[w];
        atomicAdd(&bsums[grp], tot);
    }
}

__global__ void fin_b(const float* __restrict__ bsums, float* __restrict__ out) {
    if (threadIdx.x == 0 && blockIdx.x == 0) {
        float s = 0.f;
        for (int b = 0; b < BB; ++b) s += fmaxf(bsums[b], bsums[BB + b]);
        out[0] = s * (1.0f / (float)NN);
    }
}

extern "C" void kernel_launch(void* const* d_in, const int* in_sizes, int n_in,
                              void* d_out, int out_size, void* d_ws, size_t ws_size,
                              hipStream_t stream) {
    const float* x = (const float*)d_in[0];
    const float* y = (const float*)d_in[1];
    float* out = (float*)d_out;

    char* ws = (char*)d_ws;
    float4* rawx = (float4*)ws;
    float4* rawy = rawx + NPTS;
    float4* sclx = rawy + NPTS;
    float4* scly = sclx + NPTS;
    float* ss = (float*)(scly + NPTS);           // 2*NPTS floats (x then y)
    unsigned* mind = (unsigned*)(ss + 2 * NPTS); // 2*NPTS uints
    float* bsums = (float*)(mind + 2 * NPTS);    // 16 floats

    pack_kernel<<<(2 * NPTS) / BLK, BLK, 0, stream>>>(x, y, rawx, rawy, sclx, scly,
                                                      ss, mind, bsums);
    main_kernel<<<dim3(XCHUNK * YSPLIT, BB, 2), BLK, 0, stream>>>(rawx, rawy, sclx, scly, mind);
    fin_a<<<16 * SLICES, BLK, 0, stream>>>(ss, mind, bsums);
    fin_b<<<1, 64, 0, stream>>>(bsums, out);
}

// Round 3
// 146.692 us; speedup vs baseline: 1.0713x; 1.0154x over previous
//
#include <hip/hip_runtime.h>

// Chamfer distance, B=8, N=M=8192, 3-D fp32 points.
// d2(x,y) = xx + (yy - 2 x.y). Each block packs its own target chunk into LDS
// as (-2y, yy); inner loop is 3 FMA per pair, two pairs share one v_min3.
// sqrt hoisted out (monotone). Cross-block min combine via atomicMin on an
// order-preserving uint mapping. Finalize fused via last-block counter.

#define BB 8
#define NN 8192
#define NPTS (BB*NN)      // 65536
#define YSPLIT 16
#define YC (NN/YSPLIT)    // 512
#define RX 16
#define BLK 256
#define XCHUNK (NN/(BLK*RX))   // 2

__device__ __forceinline__ unsigned f2mono(float f) {
    unsigned u = __float_as_uint(f);
    return (u & 0x80000000u) ? ~u : (u | 0x80000000u);
}
__device__ __forceinline__ float mono2f(unsigned u) {
    unsigned b = (u & 0x80000000u) ? (u ^ 0x80000000u) : ~u;
    return __uint_as_float(b);
}

// grid: (XCHUNK*YSPLIT=32, BB, 2); block: BLK
__global__ __launch_bounds__(BLK) void
main_kernel(const float* __restrict__ x, const float* __restrict__ y,
            unsigned* __restrict__ mind) {
    __shared__ float4 sh[YC + 2];        // 8 KB + pad (prefetch overrun)
    const int dir = blockIdx.z;          // 0: queries=x targets=y, 1: swapped
    const int b   = blockIdx.y;
    const int xc  = blockIdx.x >> 4;     // [0, XCHUNK)
    const int yc  = blockIdx.x & 15;     // [0, YSPLIT)
    const float* X = dir ? y : x;        // queries (raw)
    const float* Y = dir ? x : y;        // targets (raw)
    unsigned* md = mind + dir * NPTS;
    const int t = threadIdx.x;

    // pack + stage target chunk into LDS: (-2ty, tyy)
#pragma unroll
    for (int s = 0; s < YC / BLK; ++s) {
        int gi = b * NN + yc * YC + t + s * BLK;
        float f0 = Y[3*gi], f1 = Y[3*gi+1], f2 = Y[3*gi+2];
        sh[t + s * BLK] = make_float4(-2.f*f0, -2.f*f1, -2.f*f2,
                                      f0*f0 + f1*f1 + f2*f2);
    }
    if (t < 2) sh[YC + t] = make_float4(0.f, 0.f, 0.f, 0.f);
    __syncthreads();

    // RX raw query points in registers
    float qx[RX], qy[RX], qz[RX], m[RX];
    const int qg = b * NN + xc * (BLK * RX) + t;
#pragma unroll
    for (int k = 0; k < RX; ++k) {
        int i = qg + k * BLK;
        qx[k] = X[3*i]; qy[k] = X[3*i+1]; qz[k] = X[3*i+2];
        m[k] = 3.4e38f;
    }

    // software-pipelined: prefetch next 2 targets while computing current 2
    float4 a = sh[0], c = sh[1];
#pragma unroll 2
    for (int j = 0; j < YC; j += 2) {
        float4 a2 = sh[j + 2], c2 = sh[j + 3];   // prefetch (pad at end)
#pragma unroll
        for (int k = 0; k < RX; ++k) {
            float t0 = fmaf(qx[k], a.x, a.w);
            t0 = fmaf(qy[k], a.y, t0);
            t0 = fmaf(qz[k], a.z, t0);
            float t1 = fmaf(qx[k], c.x, c.w);
            t1 = fmaf(qy[k], c.y, t1);
            t1 = fmaf(qz[k], c.z, t1);
            m[k] = fminf(fminf(t0, t1), m[k]);   // v_min3_f32
        }
        a = a2; c = c2;
    }

#pragma unroll
    for (int k = 0; k < RX; ++k)
        atomicMin(&md[qg + k * BLK], f2mono(m[k]));
}

// grid: 16 blocks (dir*8+b); block BLK. Fused: per-group sum, last block
// computes the final output.
__global__ void fin_kernel(const float* __restrict__ x, const float* __restrict__ y,
                           const unsigned* __restrict__ mind,
                           float* __restrict__ bsums, unsigned* __restrict__ counter,
                           float* __restrict__ out) {
    __shared__ float red[BLK / 64];
    const int grp = blockIdx.x;            // dir*8+b
    const int dir = grp >> 3, b = grp & 7;
    const float* Q = dir ? y : x;          // queries (raw) for this direction
    const unsigned* md = mind + dir * NPTS;
    const int t = threadIdx.x;
    float s = 0.f;
#pragma unroll
    for (int k = 0; k < NN / BLK; ++k) {   // 32 iters
        int i = b * NN + t + k * BLK;
        float f0 = Q[3*i], f1 = Q[3*i+1], f2 = Q[3*i+2];
        float xx = f0*f0 + f1*f1 + f2*f2;
        s += sqrtf(xx + mono2f(md[i]) + 1e-10f);
    }
    for (int off = 32; off; off >>= 1) s += __shfl_down(s, off, 64);
    if ((t & 63) == 0) red[t >> 6] = s;
    __syncthreads();
    if (t == 0) {
        float tot = 0.f;
        for (int w = 0; w < BLK / 64; ++w) tot += red[w];
        atomicAdd(&bsums[grp], tot);
        __threadfence();
        unsigned old = atomicAdd(counter, 1u);
        if (old == 15u) {
            float acc = 0.f;
            for (int bb = 0; bb < BB; ++bb) {
                float s0 = atomicAdd(&bsums[bb], 0.f);       // coherent read
                float s1 = atomicAdd(&bsums[BB + bb], 0.f);
                acc += fmaxf(s0, s1);
            }
            out[0] = acc * (1.0f / (float)NN);
        }
    }
}

extern "C" void kernel_launch(void* const* d_in, const int* in_sizes, int n_in,
                              void* d_out, int out_size, void* d_ws, size_t ws_size,
                              hipStream_t stream) {
    const float* x = (const float*)d_in[0];
    const float* y = (const float*)d_in[1];
    float* out = (float*)d_out;

    char* ws = (char*)d_ws;
    unsigned* mind = (unsigned*)ws;              // 2*NPTS uints
    float* bsums = (float*)(mind + 2 * NPTS);    // 16 floats
    unsigned* counter = (unsigned*)(bsums + 16); // 1 uint

    hipMemsetAsync(mind, 0xFF, 2 * NPTS * sizeof(unsigned), stream);
    hipMemsetAsync(bsums, 0, 17 * sizeof(float), stream);
    main_kernel<<<dim3(XCHUNK * YSPLIT, BB, 2), BLK, 0, stream>>>(x, y, mind);
    fin_kernel<<<16, BLK, 0, stream>>>(x, y, mind, bsums, counter, out);
}

// Round 4
// 105.347 us; speedup vs baseline: 1.4918x; 1.3925x over previous
//
#include <hip/hip_runtime.h>

// Chamfer distance, B=8, N=M=8192, 3-D fp32 points — MFMA path.
// d2 = xx + yy - 2x.y computed fully inside mfma_f32_32x32x16_bf16 via
// split-precision limbs packed along K (13 of 16 slots used):
//   A row (query q):  [(-2q)h*3, (-2q)l*3, (-2q)h*3, qqh, qql, 1, 1, 0,0,0]
//   B col (target t): [ th*3,     th*3,     tl*3,    1, 1, tth, ttl, 0,0,0]
// Two passes (dir swaps A/B roles) so the needed min is always over rows,
// which is the in-lane direction of the C layout (col=lane&31, regs=rows).
// Min-tree -> LDS atomicMin per col -> global atomicMin (mono-mapped uint).

#define BB 8
#define NN 8192
#define NPTS (BB*NN)      // 65536
#define BLK 256
#define CCOLS 1024        // cols per block (LDS-staged, 32 KB encoded)
#define RROWS 512         // rows per block (128 per wave, 4 tiles of 32)
#define CT (CCOLS/32)     // 32 col-tiles per block
#define RT 4              // row-tiles per wave

typedef __attribute__((ext_vector_type(8))) short bf16x8;
typedef __attribute__((ext_vector_type(16))) float f32x16;

__device__ __forceinline__ unsigned f2mono(float f) {
    unsigned u = __float_as_uint(f);
    return u ^ ((unsigned)((int)u >> 31) | 0x80000000u);
}
__device__ __forceinline__ float mono2f(unsigned m) {
    unsigned u = ((int)m >= 0) ? ~m : (m ^ 0x80000000u);
    return __uint_as_float(u);
}
__device__ __forceinline__ unsigned short bfh(float v) {   // fp32 -> bf16 RNE
    unsigned u = __float_as_uint(v);
    u += 0x7FFFu + ((u >> 16) & 1u);
    return (unsigned short)(u >> 16);
}
__device__ __forceinline__ float bff(unsigned short h) {
    return __uint_as_float(((unsigned)h) << 16);
}

__device__ __forceinline__ void encA(float q0, float q1, float q2, unsigned short e[16]) {
    float v0 = -2.f*q0, v1 = -2.f*q1, v2 = -2.f*q2;
    float s2 = q0*q0 + q1*q1 + q2*q2;
    unsigned short h0 = bfh(v0), h1 = bfh(v1), h2 = bfh(v2);
    unsigned short l0 = bfh(v0 - bff(h0)), l1 = bfh(v1 - bff(h1)), l2 = bfh(v2 - bff(h2));
    unsigned short sh = bfh(s2), sl = bfh(s2 - bff(sh));
    const unsigned short one = 0x3F80;
    e[0]=h0; e[1]=h1; e[2]=h2; e[3]=l0; e[4]=l1; e[5]=l2; e[6]=h0; e[7]=h1;
    e[8]=h2; e[9]=sh; e[10]=sl; e[11]=one; e[12]=one; e[13]=0; e[14]=0; e[15]=0;
}
__device__ __forceinline__ void encB(float w0, float w1, float w2, unsigned short e[16]) {
    float s2 = w0*w0 + w1*w1 + w2*w2;
    unsigned short h0 = bfh(w0), h1 = bfh(w1), h2 = bfh(w2);
    unsigned short l0 = bfh(w0 - bff(h0)), l1 = bfh(w1 - bff(h1)), l2 = bfh(w2 - bff(h2));
    unsigned short sh = bfh(s2), sl = bfh(s2 - bff(sh));
    const unsigned short one = 0x3F80;
    e[0]=h0; e[1]=h1; e[2]=h2; e[3]=h0; e[4]=h1; e[5]=h2; e[6]=l0; e[7]=l1;
    e[8]=l2; e[9]=one; e[10]=one; e[11]=sh; e[12]=sl; e[13]=0; e[14]=0; e[15]=0;
}

// grid: (16 row-chunks * 8 col-chunks = 128, BB, 2 dirs); block 256
__global__ __launch_bounds__(BLK, 4) void
main_kernel(const float* __restrict__ x, const float* __restrict__ y,
            unsigned* __restrict__ mind) {
    __shared__ unsigned short benc[CCOLS * 16];  // 32 KB encoded targets
    __shared__ unsigned colmin[CCOLS];           // 4 KB
    const int dir = blockIdx.z;
    const int b   = blockIdx.y;
    const int rc  = blockIdx.x >> 3;
    const int cc  = blockIdx.x & 7;
    const float* A  = dir ? y : x;   // rows (the set we min OVER)
    const float* Bp = dir ? x : y;   // cols (the set that OWNS the mins)
    const int tid = threadIdx.x;

    // init colmin + stage/encode the 1024-col chunk into LDS
#pragma unroll
    for (int s = 0; s < CCOLS / BLK; ++s) {
        int ci = tid + s * BLK;
        colmin[ci] = 0xFFFFFFFFu;
        int gi = b * NN + cc * CCOLS + ci;
        union { unsigned short e[16]; uint4 q[2]; } u;
        encB(Bp[3*gi], Bp[3*gi+1], Bp[3*gi+2], u.e);
        ((uint4*)benc)[ci*2]     = u.q[0];
        ((uint4*)benc)[ci*2 + 1] = u.q[1];
    }

    // A fragments for this wave's 4 row-tiles (on-the-fly encode)
    const int lane = tid & 63;
    const int w    = tid >> 6;
    const int m    = lane & 31;      // row within tile / col within tile
    const int h    = lane >> 5;      // K-half: k = h*8 + j
    bf16x8 af[RT];
    const int rowbase = b * NN + rc * RROWS + w * (RT * 32);
#pragma unroll
    for (int t = 0; t < RT; ++t) {
        int r = rowbase + t * 32 + m;
        union { unsigned short e[16]; bf16x8 v[2]; } u;
        encA(A[3*r], A[3*r+1], A[3*r+2], u.e);
        af[t] = u.v[h];
    }
    __syncthreads();

    f32x16 zro;
#pragma unroll
    for (int i = 0; i < 16; ++i) zro[i] = 0.f;

    const bf16x8* bv = (const bf16x8*)benc;
    bf16x8 bf = bv[m*2 + h];                    // ct = 0
#pragma unroll 2
    for (int ct = 0; ct < CT; ++ct) {
        bf16x8 nxt = (ct + 1 < CT) ? bv[(ct+1)*64 + m*2 + h] : bf;
        f32x16 a0 = __builtin_amdgcn_mfma_f32_32x32x16_bf16(af[0], bf, zro, 0, 0, 0);
        f32x16 a1 = __builtin_amdgcn_mfma_f32_32x32x16_bf16(af[1], bf, zro, 0, 0, 0);
        f32x16 a2 = __builtin_amdgcn_mfma_f32_32x32x16_bf16(af[2], bf, zro, 0, 0, 0);
        f32x16 a3 = __builtin_amdgcn_mfma_f32_32x32x16_bf16(af[3], bf, zro, 0, 0, 0);
        float p = 3.4e38f;
#pragma unroll
        for (int r = 0; r < 16; ++r) {          // min over 64 rows (v_min3 chains)
            p = fminf(fminf(fminf(fminf(a0[r], a1[r]), a2[r]), a3[r]), p);
        }
        atomicMin(&colmin[ct*32 + m], f2mono(p));  // 2-way (free) LDS atomic
        bf = nxt;
    }
    __syncthreads();

#pragma unroll
    for (int s = 0; s < CCOLS / BLK; ++s) {
        int ci = tid + s * BLK;
        atomicMin(&mind[dir * NPTS + b * NN + cc * CCOLS + ci], colmin[ci]);
    }
}

// grid: 64 blocks = 16 (dir,b) groups x 4 slices; block BLK.
__global__ void fin_kernel(const unsigned* __restrict__ mind,
                           float* __restrict__ bsums, unsigned* __restrict__ counter,
                           float* __restrict__ out) {
    __shared__ float red[BLK / 64];
    const int grp = blockIdx.x >> 2;   // dir*8+b ; mind offset = grp*NN
    const int sl  = blockIdx.x & 3;
    const int t = threadIdx.x;
    const unsigned* md = mind + grp * NN;
    float s = 0.f;
#pragma unroll
    for (int k = 0; k < NN / 4 / BLK; ++k) {   // 8 iters
        int i = sl * (NN / 4) + t + k * BLK;
        s += sqrtf(fmaxf(mono2f(md[i]), 0.f) + 1e-10f);
    }
    for (int off = 32; off; off >>= 1) s += __shfl_down(s, off, 64);
    if ((t & 63) == 0) red[t >> 6] = s;
    __syncthreads();
    if (t == 0) {
        float tot = 0.f;
        for (int ww = 0; ww < BLK / 64; ++ww) tot += red[ww];
        atomicAdd(&bsums[grp], tot);
        __threadfence();
        unsigned old = atomicAdd(counter, 1u);
        if (old == 63u) {
            float acc = 0.f;
            for (int bb = 0; bb < BB; ++bb) {
                float s0 = atomicAdd(&bsums[bb], 0.f);       // coherent read
                float s1 = atomicAdd(&bsums[BB + bb], 0.f);
                acc += fmaxf(s0, s1);
            }
            out[0] = acc * (1.0f / (float)NN);
        }
    }
}

extern "C" void kernel_launch(void* const* d_in, const int* in_sizes, int n_in,
                              void* d_out, int out_size, void* d_ws, size_t ws_size,
                              hipStream_t stream) {
    const float* x = (const float*)d_in[0];
    const float* y = (const float*)d_in[1];
    float* out = (float*)d_out;

    char* ws = (char*)d_ws;
    unsigned* mind = (unsigned*)ws;              // 2*NPTS uints
    float* bsums = (float*)(mind + 2 * NPTS);    // 16 floats
    unsigned* counter = (unsigned*)(bsums + 16); // 1 uint

    hipMemsetAsync(mind, 0xFF, 2 * NPTS * sizeof(unsigned), stream);
    hipMemsetAsync(bsums, 0, 17 * sizeof(float), stream);
    main_kernel<<<dim3(128, BB, 2), BLK, 0, stream>>>(x, y, mind);
    fin_kernel<<<64, BLK, 0, stream>>>(mind, bsums, counter, out);
}